// Round 18
// baseline (181.013 us; speedup 1.0000x reference)
//
#include <hip/hip_runtime.h>
#include <hip/hip_bf16.h>

typedef __attribute__((ext_vector_type(8))) short s16x8;
typedef __attribute__((ext_vector_type(4))) float f32x4;
typedef __attribute__((ext_vector_type(2))) float pf2;

#define D_FEAT 512
#define SLICES 8
#define SLICE_D 64
#define ROWS 80  // rows per mlp block: grid = 20000/80 = 250 = 0.98 blocks/CU (no tail)

__device__ __forceinline__ unsigned short f2bf(float f) {
  __hip_bfloat16 h = __float2bfloat16(f);
  return *reinterpret_cast<unsigned short*>(&h);
}

__device__ __forceinline__ float bitsf(unsigned int u) {
  union { unsigned int i; float f; } c;
  c.i = u;
  return c.f;
}

__device__ __forceinline__ void async16(void* lds, const void* g) {
  __builtin_amdgcn_global_load_lds(
      (const __attribute__((address_space(1))) void*)g,
      (__attribute__((address_space(3))) void*)lds, 16, 0, 0);
}

// ---------------- zero scratch ----------------

__global__ __launch_bounds__(256) void zero_k(int4* __restrict__ p, int n16) {
  int i = blockIdx.x * 256 + threadIdx.x;
  if (i < n16) p[i] = make_int4(0, 0, 0, 0);
}

// ---------------- fused: histogram (deg) + x -> bf16 slice-major convert ----------------

__global__ __launch_bounds__(256) void hx_k(const int* __restrict__ dst, int E,
                                            int* __restrict__ deg,
                                            const float* __restrict__ x,
                                            unsigned short* __restrict__ xs, int n8, int hb,
                                            int Nn) {
  int bid = blockIdx.x;
  if (bid < hb) {
    int i = bid * 256 + threadIdx.x;
    if (i < E) atomicAdd(&deg[dst[i]], 1);
  } else {
    int i = (bid - hb) * 256 + threadIdx.x;
    if (i < n8) {
      int n = i >> 6;
      int c = i & 63;
      int s = c >> 3;
      int off = (c & 7);
      const float4* p = (const float4*)x + (size_t)i * 2;
      float4 u = p[0], v = p[1];
      s16x8 r;
      r[0] = (short)f2bf(u.x); r[1] = (short)f2bf(u.y);
      r[2] = (short)f2bf(u.z); r[3] = (short)f2bf(u.w);
      r[4] = (short)f2bf(v.x); r[5] = (short)f2bf(v.y);
      r[6] = (short)f2bf(v.z); r[7] = (short)f2bf(v.w);
      ((s16x8*)xs)[((size_t)s * Nn + n) * 8 + off] = r;
    }
  }
}

// ---------------- fused: weight transpose-convert (blocks 0..127) + scan/bucket (block 128) ----------------

__global__ __launch_bounds__(1024) void scanw_k(const int* __restrict__ deg,
                                                int* __restrict__ rowstart,
                                                unsigned short* __restrict__ nodeord, int n,
                                                const float* __restrict__ W1,
                                                const float* __restrict__ W2,
                                                unsigned short* __restrict__ W1t,
                                                unsigned short* __restrict__ W2t) {
  if (blockIdx.x < 128) {
    __shared__ float tile[64][65];
    int t = blockIdx.x;
    const float* W = W1;
    unsigned short* Wt = W1t;
    if (t >= 64) { t -= 64; W = W2; Wt = W2t; }
    int tr = (t >> 3) * 64;
    int tc = (t & 7) * 64;
    int tid = threadIdx.x;
    int c4 = (tid & 15) * 4, r = tid >> 4;  // r = 0..63
    float4 vv = *(const float4*)&W[(size_t)(tr + r) * 512 + tc + c4];
    tile[r][c4] = vv.x; tile[r][c4 + 1] = vv.y; tile[r][c4 + 2] = vv.z; tile[r][c4 + 3] = vv.w;
    __syncthreads();
    int nn = tid >> 4;
    int k0 = (tid & 15) * 4;
    ushort4 o;
    o.x = f2bf(tile[k0 + 0][nn]);
    o.y = f2bf(tile[k0 + 1][nn]);
    o.z = f2bf(tile[k0 + 2][nn]);
    o.w = f2bf(tile[k0 + 3][nn]);
    *(ushort4*)&Wt[(size_t)(tc + nn) * 512 + tr + k0] = o;
    return;
  }
  __shared__ int wsum[16];
  __shared__ int carry_s;
  __shared__ int hist[65];
  int tid = threadIdx.x;
  int lane = tid & 63, wid = tid >> 6;
  if (tid == 0) carry_s = 0;
  __syncthreads();
  for (int t0 = 0; t0 < n; t0 += 1024) {
    int i = t0 + tid;
    int v = (i < n) ? deg[i] : 0;
    int s = v;
#pragma unroll
    for (int off = 1; off < 64; off <<= 1) {
      int t = __shfl_up(s, off);
      if (lane >= off) s += t;
    }
    if (lane == 63) wsum[wid] = s;
    __syncthreads();
    if (wid == 0) {
      int ws = (lane < 16) ? wsum[lane] : 0;
#pragma unroll
      for (int off = 1; off < 16; off <<= 1) {
        int t = __shfl_up(ws, off);
        if (lane >= off) ws += t;
      }
      if (lane < 16) wsum[lane] = ws;
    }
    __syncthreads();
    int carry = carry_s;
    int wbase = (wid > 0) ? wsum[wid - 1] : 0;
    if (i < n) rowstart[i] = carry + wbase + s - v;
    int total = wsum[15];
    __syncthreads();
    if (tid == 0) carry_s = carry + total;
    __syncthreads();
  }
  if (tid == 0) rowstart[n] = carry_s;
  if (tid < 65) hist[tid] = 0;
  __syncthreads();
  for (int i = tid; i < n; i += 1024) atomicAdd(&hist[min(deg[i], 64)], 1);
  __syncthreads();
  if (tid == 0) {
    int run = 0;
    for (int b = 0; b < 65; ++b) { int c = hist[b]; hist[b] = run; run += c; }
  }
  __syncthreads();
  for (int i = tid; i < n; i += 1024) {
    int b = min(deg[i], 64);
    int pos = atomicAdd(&hist[b], 1);
    nodeord[pos] = (unsigned short)i;
  }
}

__global__ void fill_k(const int* __restrict__ src, const int* __restrict__ dst, int E,
                       const int* __restrict__ rowstart, int* __restrict__ cursor,
                       unsigned short* __restrict__ ep16) {
  int i = blockIdx.x * 256 + threadIdx.x;
  if (i < E) {
    int d = dst[i];
    int pos = atomicAdd(&cursor[d], 1);
    ep16[rowstart[d] + pos] = (unsigned short)src[i];
  }
}

// ---------------- slice-per-XCD aggregation, ILP-8, packed f32x2 accumulate ----------------

__global__ __launch_bounds__(256, 6) void agg_k(const unsigned short* __restrict__ xs,
                                                const int* __restrict__ rowstart,
                                                const unsigned short* __restrict__ ep16,
                                                const unsigned short* __restrict__ nodeord,
                                                unsigned short* __restrict__ h, int Nn) {
  int slice = blockIdx.x & 7;
  int nb = blockIdx.x >> 3;
  int wid = threadIdx.x >> 6, lane = threadIdx.x & 63;
  int g = lane >> 3, sub = lane & 7;
  int slot = (nb * 4 + wid) * 8 + g;
  int node = nodeord[slot];
  int beg = rowstart[node];
  int deg = rowstart[node + 1] - beg;
  int degm1 = max(deg - 1, 0);
  int dm = deg;
  dm = max(dm, __shfl_xor(dm, 8));
  dm = max(dm, __shfl_xor(dm, 16));
  dm = max(dm, __shfl_xor(dm, 32));
  const s16x8* sb = (const s16x8*)xs + (size_t)slice * Nn * 8;
  s16x8 own = sb[node * 8 + sub];
  pf2 acc[4];
#pragma unroll
  for (int q = 0; q < 4; ++q) {
    unsigned int d = (unsigned int)((const int*)&own)[q];
    acc[q].x = bitsf(d << 16);
    acc[q].y = bitsf(d & 0xffff0000u);
  }
  for (int t = 0; t < dm; t += 8) {
    s16x8 v[8];
    float m[8];
#pragma unroll
    for (int b = 0; b < 8; ++b) {
      int tt = t + b;
      int e = ep16[beg + min(tt, degm1)];
      m[b] = (tt < deg) ? 1.f : 0.f;
      v[b] = sb[e * 8 + sub];
    }
#pragma unroll
    for (int b = 0; b < 8; ++b) {
#pragma unroll
      for (int q = 0; q < 4; ++q) {
        unsigned int d = (unsigned int)((const int*)&v[b])[q];
        pf2 p;
        p.x = bitsf(d << 16);
        p.y = bitsf(d & 0xffff0000u);
        acc[q] += m[b] * p;  // v_pk_fma_f32 candidate
      }
    }
  }
  s16x8 r;
#pragma unroll
  for (int q = 0; q < 4; ++q) {
    r[q * 2 + 0] = (short)f2bf(acc[q].x);
    r[q * 2 + 1] = (short)f2bf(acc[q].y);
  }
  __builtin_nontemporal_store(r, (s16x8*)(h + (size_t)node * D_FEAT + slice * SLICE_D + sub * 8));
}

// ---------------- FUSED MLP v4: 1024 threads, pair-swizzled BK=32 staging ----------------
// R17 lesson: BK=32 rows are 64B, so the 2-bit chunk XOR can't spread reads
// over the 8 four-bank LDS slots -> 3.58M conflicts. Fix: PAIR-SWIZZLE. Treat
// two BK=32 rows as one 128B group of 8 slots; slot = (((row&1)<<2)|c) ^
// (pair&7) on both staging source and reads -- exactly the m97 bank pattern
// that measured 0 conflicts (R15). Linear LDS dest preserved.

__global__ __launch_bounds__(1024, 1) void mlp_k(const unsigned short* __restrict__ A,
                                                 const unsigned short* __restrict__ W1t,
                                                 const unsigned short* __restrict__ W2t,
                                                 const float* __restrict__ b1,
                                                 const float* __restrict__ b2,
                                                 float* __restrict__ out, int M) {
  __shared__ unsigned short As[2][ROWS * 32];   // 10 KB
  __shared__ unsigned short Bs[2][512 * 32];    // 64 KB
  __shared__ unsigned short c1s[ROWS * 512];    // 80 KB  (total 154 KB)
  int tm = blockIdx.x;
  int tid = threadIdx.x;
  int wave = tid >> 6, lane = tid & 63;
  int lr = lane & 15, lh = lane >> 4;
  bool aw = tid < 320;  // A-staging threads (waves 0..4)

  // pair-swizzle: LDS chunk index for tile coords (row, c)
  auto ldschunk = [](int row, int c) {
    int p = row >> 1;
    return p * 8 + (((((row & 1) << 2) | c)) ^ (p & 7));
  };

  auto stage_b = [&](const unsigned short* Bt, int pb, int k0) {
#pragma unroll
    for (int ii = 0; ii < 2; ++ii) {
      int cb = ii * 1024 + tid;  // dest chunk
      int p = cb >> 3;
      int s2 = (cb & 7) ^ (p & 7);
      int row = p * 2 + (s2 >> 2);
      int c = s2 & 3;
      async16(&Bs[pb][(size_t)(ii * 1024 + wave * 64) * 8], Bt + (size_t)row * 512 + k0 + c * 8);
    }
  };
  auto stage_a = [&](int pb, int k0) {
    if (aw) {  // 80 rows x 4 chunks = 320 chunks
      int cb = tid;
      int p = cb >> 3;
      int s2 = (cb & 7) ^ (p & 7);
      int row = p * 2 + (s2 >> 2);
      int c = s2 & 3;
      int ga = min(tm * ROWS + row, M - 1);
      async16(&As[pb][(size_t)(wave * 64) * 8], A + (size_t)ga * 512 + k0 + c * 8);
    }
  };

  f32x4 zero = {0.f, 0.f, 0.f, 0.f};
  f32x4 acc[5][2];
#pragma unroll
  for (int rt = 0; rt < 5; ++rt)
#pragma unroll
    for (int ct = 0; ct < 2; ++ct) acc[rt][ct] = zero;

  // ---- phase 1: c1 = ReLU(A @ W1 + b1) ----
  stage_b(W1t, 0, 0);
  stage_a(0, 0);
#pragma unroll
  for (int t = 0; t < 16; ++t) {
    int pb = t & 1;
    if (t < 15) { stage_b(W1t, pb ^ 1, (t + 1) * 32); stage_a(pb ^ 1, (t + 1) * 32); }
    if (t < 15) {
      if (aw) asm volatile("s_waitcnt vmcnt(3)" ::: "memory");
      else    asm volatile("s_waitcnt vmcnt(2)" ::: "memory");
    } else {
      asm volatile("s_waitcnt vmcnt(0)" ::: "memory");
    }
    __builtin_amdgcn_s_barrier();
    s16x8 av[5], bv[2];
#pragma unroll
    for (int rt = 0; rt < 5; ++rt)
      av[rt] = *(const s16x8*)&As[pb][ldschunk(rt * 16 + lr, lh) * 8];
#pragma unroll
    for (int ct = 0; ct < 2; ++ct)
      bv[ct] = *(const s16x8*)&Bs[pb][ldschunk(wave * 32 + ct * 16 + lr, lh) * 8];
#pragma unroll
    for (int rt = 0; rt < 5; ++rt)
#pragma unroll
      for (int ct = 0; ct < 2; ++ct)
        acc[rt][ct] = __builtin_amdgcn_mfma_f32_16x16x32_bf16(av[rt], bv[ct], acc[rt][ct], 0, 0, 0);
    __builtin_amdgcn_s_barrier();
  }

  // phase-2 prologue B load overlaps the c1 epilogue
  stage_b(W2t, 0, 0);

  // c1 -> LDS bf16; chunk XOR row&7 (8-slot, m97 pattern)
#pragma unroll
  for (int ct = 0; ct < 2; ++ct) {
    int col = wave * 32 + ct * 16 + lr;
    float bval = b1[col];
    int chunk = col >> 3;
#pragma unroll
    for (int rt = 0; rt < 5; ++rt) {
#pragma unroll
      for (int j = 0; j < 4; ++j) {
        int row = rt * 16 + lh * 4 + j;
        float v = fmaxf(acc[rt][ct][j] + bval, 0.f);
        c1s[row * 512 + ((chunk ^ (row & 7)) * 8) + (col & 7)] = f2bf(v);
      }
    }
  }
  __syncthreads();

  // ---- phase 2: out = c1 @ W2 + b2 ----
#pragma unroll
  for (int rt = 0; rt < 5; ++rt)
#pragma unroll
    for (int ct = 0; ct < 2; ++ct) acc[rt][ct] = zero;

#pragma unroll
  for (int t = 0; t < 16; ++t) {
    int pb = t & 1;
    if (t < 15) stage_b(W2t, pb ^ 1, (t + 1) * 32);
    if (t < 15) asm volatile("s_waitcnt vmcnt(2)" ::: "memory");
    else        asm volatile("s_waitcnt vmcnt(0)" ::: "memory");
    __builtin_amdgcn_s_barrier();
    s16x8 av[5], bv[2];
#pragma unroll
    for (int rt = 0; rt < 5; ++rt) {
      int row = rt * 16 + lr;
      av[rt] = *(const s16x8*)&c1s[row * 512 + (((t * 4 + lh) ^ (row & 7)) * 8)];
    }
#pragma unroll
    for (int ct = 0; ct < 2; ++ct)
      bv[ct] = *(const s16x8*)&Bs[pb][ldschunk(wave * 32 + ct * 16 + lr, lh) * 8];
#pragma unroll
    for (int rt = 0; rt < 5; ++rt)
#pragma unroll
      for (int ct = 0; ct < 2; ++ct)
        acc[rt][ct] = __builtin_amdgcn_mfma_f32_16x16x32_bf16(av[rt], bv[ct], acc[rt][ct], 0, 0, 0);
    __builtin_amdgcn_s_barrier();
  }

  // epilogue: C/D layout col=lane&15, row=(lane>>4)*4+j  [measured m89]
#pragma unroll
  for (int ct = 0; ct < 2; ++ct) {
    int col = wave * 32 + ct * 16 + lr;
    float bval = b2[col];
#pragma unroll
    for (int rt = 0; rt < 5; ++rt) {
#pragma unroll
      for (int j = 0; j < 4; ++j) {
        int row = tm * ROWS + rt * 16 + lh * 4 + j;
        if (row < M) out[(size_t)row * 512 + col] = acc[rt][ct][j] + bval;
      }
    }
  }
}

// ---------------- launch ----------------

extern "C" void kernel_launch(void* const* d_in, const int* in_sizes, int n_in,
                              void* d_out, int out_size, void* d_ws, size_t ws_size,
                              hipStream_t stream) {
  const float* x = (const float*)d_in[0];
  const int* ei = (const int*)d_in[1];
  const float* W1 = (const float*)d_in[2];
  const float* b1 = (const float*)d_in[3];
  const float* W2 = (const float*)d_in[4];
  const float* b2 = (const float*)d_in[5];
  const int N = in_sizes[0] / D_FEAT;  // 20000
  const int E = in_sizes[1] / 2;       // 640000
  const int* src = ei;
  const int* dst = ei + E;

  char* w = (char*)d_ws;
  auto alloc = [&](size_t bytes) {
    void* p = (void*)w;
    w += (bytes + 255) & ~(size_t)255;
    return p;
  };
  unsigned short* ep16 = (unsigned short*)alloc((size_t)E * 2 + 256);
  int* deg = (int*)alloc((size_t)N * 4);
  int* cursor = (int*)alloc((size_t)N * 4);
  int* rowstart = (int*)alloc((size_t)(N + 1) * 4);
  unsigned short* nodeord = (unsigned short*)alloc((size_t)N * 2);
  unsigned short* W1t = (unsigned short*)alloc((size_t)512 * 512 * 2);
  unsigned short* W2t = (unsigned short*)alloc((size_t)512 * 512 * 2);
  unsigned short* h = (unsigned short*)alloc((size_t)N * 512 * 2);  // h must NOT alias d_out
  // xs (slice-major bf16 x) = upper half of d_out; dead before mlp_k writes out.
  unsigned short* xs = (unsigned short*)d_out + (size_t)N * D_FEAT;

  size_t zbytes = (size_t)((char*)cursor - (char*)deg) + (size_t)N * 4;
  int zn16 = (int)(zbytes / 16);
  zero_k<<<(zn16 + 255) / 256, 256, 0, stream>>>((int4*)deg, zn16);
  int hb = (E + 255) / 256;
  int n8 = N * D_FEAT / 8;
  int xbk = (n8 + 255) / 256;
  hx_k<<<hb + xbk, 256, 0, stream>>>(dst, E, deg, x, xs, n8, hb, N);
  scanw_k<<<129, 1024, 0, stream>>>(deg, rowstart, nodeord, N, W1, W2, W1t, W2t);
  fill_k<<<hb, 256, 0, stream>>>(src, dst, E, rowstart, cursor, ep16);
  agg_k<<<8 * (N / 32), 256, 0, stream>>>(xs, rowstart, ep16, nodeord, h, N);
  int mt = (N + ROWS - 1) / ROWS;  // 250
  mlp_k<<<mt, 1024, 0, stream>>>(h, W1t, W2t, b1, b2, (float*)d_out, N);
}

// Round 19
// 172.464 us; speedup vs baseline: 1.0496x; 1.0496x over previous
//
#include <hip/hip_runtime.h>
#include <hip/hip_bf16.h>

typedef __attribute__((ext_vector_type(8))) short s16x8;
typedef __attribute__((ext_vector_type(4))) float f32x4;
typedef __attribute__((ext_vector_type(2))) float pf2;

#define D_FEAT 512
#define SLICES 8
#define SLICE_D 64
#define ROWS 80  // rows per mlp block: grid = 20000/80 = 250 = 0.98 blocks/CU (no tail)

__device__ __forceinline__ unsigned short f2bf(float f) {
  __hip_bfloat16 h = __float2bfloat16(f);
  return *reinterpret_cast<unsigned short*>(&h);
}

__device__ __forceinline__ float bitsf(unsigned int u) {
  union { unsigned int i; float f; } c;
  c.i = u;
  return c.f;
}

__device__ __forceinline__ void async16(void* lds, const void* g) {
  __builtin_amdgcn_global_load_lds(
      (const __attribute__((address_space(1))) void*)g,
      (__attribute__((address_space(3))) void*)lds, 16, 0, 0);
}

// ---------------- zero scratch ----------------

__global__ __launch_bounds__(256) void zero_k(int4* __restrict__ p, int n16) {
  int i = blockIdx.x * 256 + threadIdx.x;
  if (i < n16) p[i] = make_int4(0, 0, 0, 0);
}

// ---------------- fused: histogram (deg) + x -> bf16 slice-major convert ----------------

__global__ __launch_bounds__(256) void hx_k(const int* __restrict__ dst, int E,
                                            int* __restrict__ deg,
                                            const float* __restrict__ x,
                                            unsigned short* __restrict__ xs, int n8, int hb,
                                            int Nn) {
  int bid = blockIdx.x;
  if (bid < hb) {
    int i = bid * 256 + threadIdx.x;
    if (i < E) atomicAdd(&deg[dst[i]], 1);
  } else {
    int i = (bid - hb) * 256 + threadIdx.x;
    if (i < n8) {
      int n = i >> 6;
      int c = i & 63;
      int s = c >> 3;
      int off = (c & 7);
      const float4* p = (const float4*)x + (size_t)i * 2;
      float4 u = p[0], v = p[1];
      s16x8 r;
      r[0] = (short)f2bf(u.x); r[1] = (short)f2bf(u.y);
      r[2] = (short)f2bf(u.z); r[3] = (short)f2bf(u.w);
      r[4] = (short)f2bf(v.x); r[5] = (short)f2bf(v.y);
      r[6] = (short)f2bf(v.z); r[7] = (short)f2bf(v.w);
      ((s16x8*)xs)[((size_t)s * Nn + n) * 8 + off] = r;
    }
  }
}

// ---------------- fused: weight transpose-convert (blocks 0..127) + scan/bucket (block 128) ----------------
// Scan vectorized: 4 elements/thread (int4) -> 5 block iterations instead of 20.

__global__ __launch_bounds__(1024) void scanw_k(const int* __restrict__ deg,
                                                int* __restrict__ rowstart,
                                                unsigned short* __restrict__ nodeord, int n,
                                                const float* __restrict__ W1,
                                                const float* __restrict__ W2,
                                                unsigned short* __restrict__ W1t,
                                                unsigned short* __restrict__ W2t) {
  if (blockIdx.x < 128) {
    __shared__ float tile[64][65];
    int t = blockIdx.x;
    const float* W = W1;
    unsigned short* Wt = W1t;
    if (t >= 64) { t -= 64; W = W2; Wt = W2t; }
    int tr = (t >> 3) * 64;
    int tc = (t & 7) * 64;
    int tid = threadIdx.x;
    int c4 = (tid & 15) * 4, r = tid >> 4;  // r = 0..63
    float4 vv = *(const float4*)&W[(size_t)(tr + r) * 512 + tc + c4];
    tile[r][c4] = vv.x; tile[r][c4 + 1] = vv.y; tile[r][c4 + 2] = vv.z; tile[r][c4 + 3] = vv.w;
    __syncthreads();
    int nn = tid >> 4;
    int k0 = (tid & 15) * 4;
    ushort4 o;
    o.x = f2bf(tile[k0 + 0][nn]);
    o.y = f2bf(tile[k0 + 1][nn]);
    o.z = f2bf(tile[k0 + 2][nn]);
    o.w = f2bf(tile[k0 + 3][nn]);
    *(ushort4*)&Wt[(size_t)(tc + nn) * 512 + tr + k0] = o;
    return;
  }
  __shared__ int wsum[16];
  __shared__ int carry_s;
  __shared__ int hist[65];
  int tid = threadIdx.x;
  int lane = tid & 63, wid = tid >> 6;
  if (tid == 0) carry_s = 0;
  __syncthreads();
  for (int t0 = 0; t0 < n; t0 += 4096) {
    int base = t0 + tid * 4;
    int e0, e1, e2, e3;
    if (base + 3 < n) {
      int4 v4 = *(const int4*)&deg[base];
      e0 = v4.x; e1 = v4.y; e2 = v4.z; e3 = v4.w;
    } else {
      e0 = (base + 0 < n) ? deg[base + 0] : 0;
      e1 = (base + 1 < n) ? deg[base + 1] : 0;
      e2 = (base + 2 < n) ? deg[base + 2] : 0;
      e3 = (base + 3 < n) ? deg[base + 3] : 0;
    }
    int lsum = e0 + e1 + e2 + e3;
    int s = lsum;  // inclusive wave scan of per-thread sums
#pragma unroll
    for (int off = 1; off < 64; off <<= 1) {
      int t = __shfl_up(s, off);
      if (lane >= off) s += t;
    }
    if (lane == 63) wsum[wid] = s;
    __syncthreads();
    if (wid == 0) {
      int ws = (lane < 16) ? wsum[lane] : 0;
#pragma unroll
      for (int off = 1; off < 16; off <<= 1) {
        int t = __shfl_up(ws, off);
        if (lane >= off) ws += t;
      }
      if (lane < 16) wsum[lane] = ws;
    }
    __syncthreads();
    int carry = carry_s;
    int wbase = (wid > 0) ? wsum[wid - 1] : 0;
    int pre = carry + wbase + (s - lsum);  // exclusive prefix at base
    if (base + 0 < n) rowstart[base + 0] = pre;
    if (base + 1 < n) rowstart[base + 1] = pre + e0;
    if (base + 2 < n) rowstart[base + 2] = pre + e0 + e1;
    if (base + 3 < n) rowstart[base + 3] = pre + e0 + e1 + e2;
    int total = wsum[15];
    __syncthreads();
    if (tid == 0) carry_s = carry + total;
    __syncthreads();
  }
  if (tid == 0) rowstart[n] = carry_s;
  // ---- degree bucketing: nodeord = node ids sorted by min(deg,64) ----
  if (tid < 65) hist[tid] = 0;
  __syncthreads();
  for (int i = tid; i < n; i += 1024) atomicAdd(&hist[min(deg[i], 64)], 1);
  __syncthreads();
  if (tid == 0) {
    int run = 0;
    for (int b = 0; b < 65; ++b) { int c = hist[b]; hist[b] = run; run += c; }
  }
  __syncthreads();
  for (int i = tid; i < n; i += 1024) {
    int b = min(deg[i], 64);
    int pos = atomicAdd(&hist[b], 1);
    nodeord[pos] = (unsigned short)i;
  }
}

__global__ void fill_k(const int* __restrict__ src, const int* __restrict__ dst, int E,
                       const int* __restrict__ rowstart, int* __restrict__ cursor,
                       unsigned short* __restrict__ ep16) {
  int i = blockIdx.x * 256 + threadIdx.x;
  if (i < E) {
    int d = dst[i];
    int pos = atomicAdd(&cursor[d], 1);
    ep16[rowstart[d] + pos] = (unsigned short)src[i];
  }
}

// ---------------- slice-per-XCD aggregation, ILP-8, packed f32x2 accumulate ----------------

__global__ __launch_bounds__(256, 6) void agg_k(const unsigned short* __restrict__ xs,
                                                const int* __restrict__ rowstart,
                                                const unsigned short* __restrict__ ep16,
                                                const unsigned short* __restrict__ nodeord,
                                                unsigned short* __restrict__ h, int Nn) {
  int slice = blockIdx.x & 7;
  int nb = blockIdx.x >> 3;
  int wid = threadIdx.x >> 6, lane = threadIdx.x & 63;
  int g = lane >> 3, sub = lane & 7;
  int slot = (nb * 4 + wid) * 8 + g;
  int node = nodeord[slot];
  int beg = rowstart[node];
  int deg = rowstart[node + 1] - beg;
  int degm1 = max(deg - 1, 0);
  int dm = deg;
  dm = max(dm, __shfl_xor(dm, 8));
  dm = max(dm, __shfl_xor(dm, 16));
  dm = max(dm, __shfl_xor(dm, 32));
  const unsigned short* ep = ep16 + beg;
  const s16x8* sb = (const s16x8*)xs + (size_t)slice * Nn * 8;
  s16x8 own = sb[node * 8 + sub];
  pf2 acc[4];
#pragma unroll
  for (int q = 0; q < 4; ++q) {
    unsigned int d = (unsigned int)((const int*)&own)[q];
    acc[q].x = bitsf(d << 16);
    acc[q].y = bitsf(d & 0xffff0000u);
  }
  for (int t = 0; t < dm; t += 8) {
    s16x8 v[8];
    float m[8];
#pragma unroll
    for (int b = 0; b < 8; ++b) {
      int tt = t + b;
      int e = ep[min(tt, degm1)];
      m[b] = (tt < deg) ? 1.f : 0.f;
      v[b] = sb[e * 8 + sub];
    }
#pragma unroll
    for (int b = 0; b < 8; ++b) {
#pragma unroll
      for (int q = 0; q < 4; ++q) {
        unsigned int d = (unsigned int)((const int*)&v[b])[q];
        pf2 p;
        p.x = bitsf(d << 16);
        p.y = bitsf(d & 0xffff0000u);
        acc[q] += m[b] * p;  // v_pk_fma_f32 candidate
      }
    }
  }
  s16x8 r;
#pragma unroll
  for (int q = 0; q < 4; ++q) {
    r[q * 2 + 0] = (short)f2bf(acc[q].x);
    r[q * 2 + 1] = (short)f2bf(acc[q].y);
  }
  __builtin_nontemporal_store(r, (s16x8*)(h + (size_t)node * D_FEAT + slice * SLICE_D + sub * 8));
}

// ---------------- FUSED MLP v4: 1024 threads, pair-swizzled BK=32 staging ----------------
// LDS-read BW (~15us: 16x duplication of the shared A fragments) + L2 B-traffic
// (~7us) + MFMA (~7us) put this near its structural floor for the
// one-block-per-CU fused shape. Output stores nontemporal (streaming 41MB
// fp32; keep W/c1 resident in L2).

__global__ __launch_bounds__(1024, 1) void mlp_k(const unsigned short* __restrict__ A,
                                                 const unsigned short* __restrict__ W1t,
                                                 const unsigned short* __restrict__ W2t,
                                                 const float* __restrict__ b1,
                                                 const float* __restrict__ b2,
                                                 float* __restrict__ out, int M) {
  __shared__ unsigned short As[2][ROWS * 32];   // 10 KB
  __shared__ unsigned short Bs[2][512 * 32];    // 64 KB
  __shared__ unsigned short c1s[ROWS * 512];    // 80 KB  (total 154 KB)
  int tm = blockIdx.x;
  int tid = threadIdx.x;
  int wave = tid >> 6, lane = tid & 63;
  int lr = lane & 15, lh = lane >> 4;
  bool aw = tid < 320;  // A-staging threads (waves 0..4)

  // pair-swizzle: LDS chunk index for tile coords (row, c)
  auto ldschunk = [](int row, int c) {
    int p = row >> 1;
    return p * 8 + (((((row & 1) << 2) | c)) ^ (p & 7));
  };

  auto stage_b = [&](const unsigned short* Bt, int pb, int k0) {
#pragma unroll
    for (int ii = 0; ii < 2; ++ii) {
      int cb = ii * 1024 + tid;  // dest chunk
      int p = cb >> 3;
      int s2 = (cb & 7) ^ (p & 7);
      int row = p * 2 + (s2 >> 2);
      int c = s2 & 3;
      async16(&Bs[pb][(size_t)(ii * 1024 + wave * 64) * 8], Bt + (size_t)row * 512 + k0 + c * 8);
    }
  };
  auto stage_a = [&](int pb, int k0) {
    if (aw) {  // 80 rows x 4 chunks = 320 chunks
      int cb = tid;
      int p = cb >> 3;
      int s2 = (cb & 7) ^ (p & 7);
      int row = p * 2 + (s2 >> 2);
      int c = s2 & 3;
      int ga = min(tm * ROWS + row, M - 1);
      async16(&As[pb][(size_t)(wave * 64) * 8], A + (size_t)ga * 512 + k0 + c * 8);
    }
  };

  f32x4 zero = {0.f, 0.f, 0.f, 0.f};
  f32x4 acc[5][2];
#pragma unroll
  for (int rt = 0; rt < 5; ++rt)
#pragma unroll
    for (int ct = 0; ct < 2; ++ct) acc[rt][ct] = zero;

  // ---- phase 1: c1 = ReLU(A @ W1 + b1) ----
  stage_b(W1t, 0, 0);
  stage_a(0, 0);
#pragma unroll
  for (int t = 0; t < 16; ++t) {
    int pb = t & 1;
    if (t < 15) { stage_b(W1t, pb ^ 1, (t + 1) * 32); stage_a(pb ^ 1, (t + 1) * 32); }
    if (t < 15) {
      if (aw) asm volatile("s_waitcnt vmcnt(3)" ::: "memory");
      else    asm volatile("s_waitcnt vmcnt(2)" ::: "memory");
    } else {
      asm volatile("s_waitcnt vmcnt(0)" ::: "memory");
    }
    __builtin_amdgcn_s_barrier();
    s16x8 av[5], bv[2];
#pragma unroll
    for (int rt = 0; rt < 5; ++rt)
      av[rt] = *(const s16x8*)&As[pb][ldschunk(rt * 16 + lr, lh) * 8];
#pragma unroll
    for (int ct = 0; ct < 2; ++ct)
      bv[ct] = *(const s16x8*)&Bs[pb][ldschunk(wave * 32 + ct * 16 + lr, lh) * 8];
#pragma unroll
    for (int rt = 0; rt < 5; ++rt)
#pragma unroll
      for (int ct = 0; ct < 2; ++ct)
        acc[rt][ct] = __builtin_amdgcn_mfma_f32_16x16x32_bf16(av[rt], bv[ct], acc[rt][ct], 0, 0, 0);
    __builtin_amdgcn_s_barrier();
  }

  // phase-2 prologue B load overlaps the c1 epilogue
  stage_b(W2t, 0, 0);

  // c1 -> LDS bf16; chunk XOR row&7 (8-slot, m97 pattern)
#pragma unroll
  for (int ct = 0; ct < 2; ++ct) {
    int col = wave * 32 + ct * 16 + lr;
    float bval = b1[col];
    int chunk = col >> 3;
#pragma unroll
    for (int rt = 0; rt < 5; ++rt) {
#pragma unroll
      for (int j = 0; j < 4; ++j) {
        int row = rt * 16 + lh * 4 + j;
        float v = fmaxf(acc[rt][ct][j] + bval, 0.f);
        c1s[row * 512 + ((chunk ^ (row & 7)) * 8) + (col & 7)] = f2bf(v);
      }
    }
  }
  __syncthreads();

  // ---- phase 2: out = c1 @ W2 + b2 ----
#pragma unroll
  for (int rt = 0; rt < 5; ++rt)
#pragma unroll
    for (int ct = 0; ct < 2; ++ct) acc[rt][ct] = zero;

#pragma unroll
  for (int t = 0; t < 16; ++t) {
    int pb = t & 1;
    if (t < 15) stage_b(W2t, pb ^ 1, (t + 1) * 32);
    if (t < 15) asm volatile("s_waitcnt vmcnt(2)" ::: "memory");
    else        asm volatile("s_waitcnt vmcnt(0)" ::: "memory");
    __builtin_amdgcn_s_barrier();
    s16x8 av[5], bv[2];
#pragma unroll
    for (int rt = 0; rt < 5; ++rt) {
      int row = rt * 16 + lr;
      av[rt] = *(const s16x8*)&c1s[row * 512 + (((t * 4 + lh) ^ (row & 7)) * 8)];
    }
#pragma unroll
    for (int ct = 0; ct < 2; ++ct)
      bv[ct] = *(const s16x8*)&Bs[pb][ldschunk(wave * 32 + ct * 16 + lr, lh) * 8];
#pragma unroll
    for (int rt = 0; rt < 5; ++rt)
#pragma unroll
      for (int ct = 0; ct < 2; ++ct)
        acc[rt][ct] = __builtin_amdgcn_mfma_f32_16x16x32_bf16(av[rt], bv[ct], acc[rt][ct], 0, 0, 0);
    __builtin_amdgcn_s_barrier();
  }

  // epilogue: C/D layout col=lane&15, row=(lane>>4)*4+j  [measured m89]
#pragma unroll
  for (int ct = 0; ct < 2; ++ct) {
    int col = wave * 32 + ct * 16 + lr;
    float bval = b2[col];
#pragma unroll
    for (int rt = 0; rt < 5; ++rt) {
#pragma unroll
      for (int j = 0; j < 4; ++j) {
        int row = tm * ROWS + rt * 16 + lh * 4 + j;
        if (row < M)
          __builtin_nontemporal_store(acc[rt][ct][j] + bval, &out[(size_t)row * 512 + col]);
      }
    }
  }
}

// ---------------- launch ----------------

extern "C" void kernel_launch(void* const* d_in, const int* in_sizes, int n_in,
                              void* d_out, int out_size, void* d_ws, size_t ws_size,
                              hipStream_t stream) {
  const float* x = (const float*)d_in[0];
  const int* ei = (const int*)d_in[1];
  const float* W1 = (const float*)d_in[2];
  const float* b1 = (const float*)d_in[3];
  const float* W2 = (const float*)d_in[4];
  const float* b2 = (const float*)d_in[5];
  const int N = in_sizes[0] / D_FEAT;  // 20000
  const int E = in_sizes[1] / 2;       // 640000
  const int* src = ei;
  const int* dst = ei + E;

  char* w = (char*)d_ws;
  auto alloc = [&](size_t bytes) {
    void* p = (void*)w;
    w += (bytes + 255) & ~(size_t)255;
    return p;
  };
  unsigned short* ep16 = (unsigned short*)alloc((size_t)E * 2 + 256);
  int* deg = (int*)alloc((size_t)N * 4);
  int* cursor = (int*)alloc((size_t)N * 4);
  int* rowstart = (int*)alloc((size_t)(N + 1) * 4);
  unsigned short* nodeord = (unsigned short*)alloc((size_t)N * 2);
  unsigned short* W1t = (unsigned short*)alloc((size_t)512 * 512 * 2);
  unsigned short* W2t = (unsigned short*)alloc((size_t)512 * 512 * 2);
  unsigned short* h = (unsigned short*)alloc((size_t)N * 512 * 2);  // h must NOT alias d_out
  // xs (slice-major bf16 x) = upper half of d_out; dead before mlp_k writes out.
  unsigned short* xs = (unsigned short*)d_out + (size_t)N * D_FEAT;

  size_t zbytes = (size_t)((char*)cursor - (char*)deg) + (size_t)N * 4;
  int zn16 = (int)(zbytes / 16);
  zero_k<<<(zn16 + 255) / 256, 256, 0, stream>>>((int4*)deg, zn16);
  int hb = (E + 255) / 256;
  int n8 = N * D_FEAT / 8;
  int xbk = (n8 + 255) / 256;
  hx_k<<<hb + xbk, 256, 0, stream>>>(dst, E, deg, x, xs, n8, hb, N);
  scanw_k<<<129, 1024, 0, stream>>>(deg, rowstart, nodeord, N, W1, W2, W1t, W2t);
  fill_k<<<hb, 256, 0, stream>>>(src, dst, E, rowstart, cursor, ep16);
  agg_k<<<8 * (N / 32), 256, 0, stream>>>(xs, rowstart, ep16, nodeord, h, N);
  int mt = (N + ROWS - 1) / ROWS;  // 250
  mlp_k<<<mt, 1024, 0, stream>>>(h, W1t, W2t, b1, b2, (float*)d_out, N);
}